// Round 6
// baseline (59.456 us; speedup 1.0000x reference)
//
#include <hip/hip_runtime.h>
#include <hip/hip_bf16.h>
#include <stdint.h>

// Problem constants: B=2, L=2048, E=1024, H=16, HD=64, G=4.
#define L_SEQ 2048
#define MTOT  4096   // B*L
#define EDIM  1024

typedef __attribute__((ext_vector_type(8))) short bf16x8;   // 8 bf16 (4 VGPRs)
typedef __attribute__((ext_vector_type(4))) float f32x4;
typedef __attribute__((ext_vector_type(4))) float float4v;
typedef __attribute__((ext_vector_type(4))) unsigned short us4;
typedef __attribute__((ext_vector_type(2))) unsigned int u32x2;

__device__ __forceinline__ unsigned short f2b(float f) {
    union { float f; unsigned u; } v; v.f = f;
    return (unsigned short)((v.u + 0x7FFFu + ((v.u >> 16) & 1u)) >> 16);  // RNE
}
__device__ __forceinline__ float b2f(unsigned short h) {
    union { unsigned u; float f; } v; v.u = ((unsigned)h) << 16;
    return v.f;
}
__device__ __forceinline__ bf16x8 pack8(f32x4 lo, f32x4 hi) {
    bf16x8 o;
    o[0] = (short)f2b(lo[0]); o[1] = (short)f2b(lo[1]);
    o[2] = (short)f2b(lo[2]); o[3] = (short)f2b(lo[3]);
    o[4] = (short)f2b(hi[0]); o[5] = (short)f2b(hi[1]);
    o[6] = (short)f2b(hi[2]); o[7] = (short)f2b(hi[3]);
    return o;
}

// ---------------------------------------------------------------------------
// wprep: convert W1 (stitched [Wv rows 0..255 ; Wq rows 256..1023]) and Wo
//        to bf16. Blocks >= 2048 compute the composed FIR taps.
// ---------------------------------------------------------------------------
__global__ __launch_bounds__(256) void wprep_kernel(
    const float* __restrict__ Wq, const float* __restrict__ Wv,
    const float* __restrict__ Wo,
    unsigned short* __restrict__ W1b, unsigned short* __restrict__ Wob,
    const float* __restrict__ q3w, const float* __restrict__ q3b,
    const float* __restrict__ v3w, const float* __restrict__ v3b,
    const float* __restrict__ q5w, const float* __restrict__ q5b,
    const float* __restrict__ v5w, const float* __restrict__ v5b,
    const float* __restrict__ q7w, const float* __restrict__ q7b,
    const float* __restrict__ v7w, const float* __restrict__ v7b,
    float* __restrict__ H, float* __restrict__ Beff, float* __restrict__ Corr)
{
    if (blockIdx.x >= 2048) {
        // taps: compose the two causal depthwise convs per channel.
        //   dwconv taps h[i] = w[k-1-i]; chain h = hq (*) hv (len 2k-1<=13),
        //   beff = vb + qb*sum(vw); boundary (l<k-1): intermediate zero-pad
        //   drops qb for taps i>l -> Corr[l][ch] = qb*sum_{i=l+1..} hv[i].
        int ch = (blockIdx.x - 2048) * 256 + threadIdx.x;   // [0,768)
        int g = ch >> 8;          // 0,1,2 -> ksz 3,5,7
        int d = ch & 63;
        int k = 3 + 2 * g;
        const float* qw = (g == 0) ? q3w : (g == 1) ? q5w : q7w;
        const float* qb = (g == 0) ? q3b : (g == 1) ? q5b : q7b;
        const float* vw = (g == 0) ? v3w : (g == 1) ? v5w : v7w;
        const float* vb = (g == 0) ? v3b : (g == 1) ? v5b : v7b;

        float hq[7], hv[7];
        for (int i = 0; i < 7; ++i) { hq[i] = 0.f; hv[i] = 0.f; }
        for (int i = 0; i < k; ++i) {
            hq[i] = qw[d * k + (k - 1 - i)];
            hv[i] = vw[d * k + (k - 1 - i)];
        }
        float h[13];
        for (int i = 0; i < 13; ++i) h[i] = 0.f;
        for (int a = 0; a < 7; ++a)
            for (int b = 0; b < 7; ++b)
                h[a + b] += hq[a] * hv[b];
        for (int i = 0; i < 13; ++i) H[i * 768 + ch] = h[i];

        float sv = 0.f;
        for (int j = 0; j < k; ++j) sv += vw[d * k + j];
        Beff[ch] = qb[d] * sv + vb[d];

        for (int l = 0; l < 6; ++l) {
            float s2 = 0.f;
            for (int i = l + 1; i < 7; ++i) s2 += hv[i];
            Corr[l * 768 + ch] = qb[d] * s2;
        }
        return;
    }
    const int WQ = (EDIM * EDIM) / 4;   // 262,144 quads per matrix
    int i = blockIdx.x * 256 + threadIdx.x;
    const float* src;
    unsigned short* dst;
    int j;
    if (i < WQ) {
        j = i * 4;
        int row = j >> 10;                 // /1024
        src = (row < 256) ? Wv : Wq;       // stitched W1
        dst = W1b;
    } else {
        j = (i - WQ) * 4; src = Wo; dst = Wob;
    }
    float4v v = *(const float4v*)(src + j);
    us4 o;
    o[0] = f2b(v[0]); o[1] = f2b(v[1]); o[2] = f2b(v[2]); o[3] = f2b(v[3]);
    *(us4*)(dst + j) = o;
}

// ---------------------------------------------------------------------------
// GEMM, reg-staged (T14): C[M,N] = A[M,K] * BT[N,K]^T.
//   BM=128, BN=64, BK=64, 512 thr = 8 waves: 2x2 spatial x 2 K-halves (kh),
//   wave tile 64x32, acc 4x2 of mfma_f32_16x16x32_bf16 (K-split merge in LDS).
//   Staging: global_load_dwordx4 -> VGPR banks -> (cvt) -> ds_write. The
//   compiler tracks vmcnt per-REGISTER precisely (unlike global_load_lds ->
//   ds_read aliasing, which forces a conservative vmcnt(0) drain every tile).
//   2 LDS buffers (48KB) + 2 reg banks; bank loads issue ~2 iterations before
//   their ds_write -> ~2 compute phases of latency cover. Raw s_barrier +
//   manual lgkmcnt(0) after ds_write (NO __syncthreads mid-loop: it drains
//   vmcnt(0) and would kill the in-flight banks).
//   TA=1: A is fp32 (x), converted in-register. TA=0: A is bf16.
//   Swizzle: 16B col-group g of row r at g^(r&7) on ds_write AND ds_read.
// OUT_MODE 0: bf16 store. OUT_MODE 1: f32 store + bias[col].
// ---------------------------------------------------------------------------
template <int TA, int OUT_MODE>
__global__ __launch_bounds__(512, 4) void gemm_rs(
    const float* __restrict__ Af, const unsigned short* __restrict__ Ab,
    const unsigned short* __restrict__ BT,
    unsigned short* __restrict__ Cb, float* __restrict__ Cf,
    const float* __restrict__ bias, int M, int N, int K)
{
    __shared__ unsigned short sh[2 * 12288];   // buf: A 8192 + B 4096 shorts

    // XCD-aware remap (512 blocks, %8==0 -> bijective).
    const int nbx = N >> 6;                       // 16
    int orig = blockIdx.y * nbx + blockIdx.x;
    int nwg  = (M >> 7) * nbx;                    // 512
    int wg   = (orig & 7) * (nwg >> 3) + (orig >> 3);
    const int m0 = (wg / nbx) * 128, n0 = (wg % nbx) * 64;

    const int tid  = threadIdx.x;
    const int wid  = tid >> 6;                    // 0..7
    const int lane = tid & 63;
    const int wr   = wid >> 2;                    // 2x2 spatial
    const int wc   = (wid >> 1) & 1;
    const int kh   = wid & 1;                     // K-half
    const int fr   = lane & 15, fq = lane >> 4;

    f32x4 acc[4][2] = {};

    // staging geometry: A tile 128x64 = 1024 16B-chunks (thread: r,g and r+64,g);
    // B tile 64x64 = 512 chunks (thread: r,g).  r = tid>>3 in [0,64), g = tid&7.
    const int r = tid >> 3, g = tid & 7;
    const int dstA0 = r * 64 + ((g ^ (r & 7)) * 8);
    const int dstA1 = dstA0 + 64 * 64;            // (r+64)&7 == r&7
    const int dstB  = dstA0;

    const size_t gA = (size_t)(m0 + r) * K + g * 8;
    const size_t gA2 = gA + (size_t)64 * K;
    const size_t gB = (size_t)(n0 + r) * K + g * 8;

    // two static register banks (rule #20: no runtime-indexed arrays)
    f32x4 al0_0, ah0_0, al1_0, ah1_0; bf16x8 aa0_0, aa1_0, bb_0;
    f32x4 al0_1, ah0_1, al1_1, ah1_1; bf16x8 aa0_1, aa1_1, bb_1;

#define LOADBANK(BK_, t_) do {                                            \
        if (TA == 1) {                                                    \
            const float* Ag = Af + gA + ((t_) << 6);                      \
            al0_##BK_ = *(const f32x4*)(Ag);                              \
            ah0_##BK_ = *(const f32x4*)(Ag + 4);                          \
            al1_##BK_ = *(const f32x4*)(Af + gA2 + ((t_) << 6));          \
            ah1_##BK_ = *(const f32x4*)(Af + gA2 + ((t_) << 6) + 4);      \
        } else {                                                          \
            aa0_##BK_ = *(const bf16x8*)(Ab + gA + ((t_) << 6));          \
            aa1_##BK_ = *(const bf16x8*)(Ab + gA2 + ((t_) << 6));         \
        }                                                                 \
        bb_##BK_ = *(const bf16x8*)(BT + gB + ((t_) << 6));               \
    } while (0)

#define DSWRITE(BK_, buf_) do {                                           \
        unsigned short* Al = sh + (buf_) * 12288;                         \
        unsigned short* Bl = Al + 8192;                                   \
        if (TA == 1) {                                                    \
            *(bf16x8*)(Al + dstA0) = pack8(al0_##BK_, ah0_##BK_);         \
            *(bf16x8*)(Al + dstA1) = pack8(al1_##BK_, ah1_##BK_);         \
        } else {                                                          \
            *(bf16x8*)(Al + dstA0) = aa0_##BK_;                           \
            *(bf16x8*)(Al + dstA1) = aa1_##BK_;                           \
        }                                                                 \
        *(bf16x8*)(Bl + dstB) = bb_##BK_;                                 \
        asm volatile("s_waitcnt lgkmcnt(0)" ::: "memory");                \
    } while (0)

    auto compute = [&](int buf) {
        const unsigned short* as = sh + buf * 12288;
        const unsigned short* bs = as + 8192;
        bf16x8 a[4], b[2];
#pragma unroll
        for (int mi = 0; mi < 4; ++mi) {
            int row = wr * 64 + mi * 16 + fr;
            a[mi] = *(const bf16x8*)(as + row * 64 + (((kh * 4 + fq) ^ (row & 7)) * 8));
        }
#pragma unroll
        for (int ni = 0; ni < 2; ++ni) {
            int row = wc * 32 + ni * 16 + fr;
            b[ni] = *(const bf16x8*)(bs + row * 64 + (((kh * 4 + fq) ^ (row & 7)) * 8));
        }
#pragma unroll
        for (int mi = 0; mi < 4; ++mi)
#pragma unroll
            for (int ni = 0; ni < 2; ++ni)
                acc[mi][ni] = __builtin_amdgcn_mfma_f32_16x16x32_bf16(a[mi], b[ni], acc[mi][ni], 0, 0, 0);
    };

    const int NT = K >> 6;   // 16 K-tiles (even, >= 6)
    // prologue: buf0<-t0, buf1<-t1; banks hold t2,t3.
    LOADBANK(0, 0);
    LOADBANK(1, 1);
    DSWRITE(0, 0);           // auto s_waitcnt on bank0 regs only
    LOADBANK(0, 2);
    DSWRITE(1, 1);
    LOADBANK(1, 3);
    __builtin_amdgcn_s_barrier();

    for (int tt = 0; tt < NT; tt += 2) {
        compute(0);
        __builtin_amdgcn_s_barrier();             // all waves done reading buf0
        if (tt + 2 < NT) DSWRITE(0, 0);           // buf0 <- tile tt+2 (bank0)
        if (tt + 4 < NT) LOADBANK(0, tt + 4);     // refill bank0
        __builtin_amdgcn_s_barrier();             // buf0 visible

        compute(1);
        __builtin_amdgcn_s_barrier();
        if (tt + 3 < NT) DSWRITE(1, 1);
        if (tt + 5 < NT) LOADBANK(1, tt + 5);
        __builtin_amdgcn_s_barrier();
    }
#undef LOADBANK
#undef DSWRITE

    // ---- K-split merge: kh=1 dumps partials to LDS, kh=0 adds & stores. ----
    __syncthreads();   // safe: no in-flight loads remain
    float* Mg = (float*)sh;                        // 32 KB
    const int mgq = (wr * 2 + wc) * 2048;          // per 64x32 quadrant
    if (kh) {
#pragma unroll
        for (int mi = 0; mi < 4; ++mi)
#pragma unroll
            for (int ni = 0; ni < 2; ++ni) {
                int col = ni * 16 + fr;
                int adr = mgq + col * 64 + (((mi * 4 + fq) ^ (col & 15)) << 2);
                *(f32x4*)(Mg + adr) = acc[mi][ni];
            }
    }
    __syncthreads();
    if (!kh) {
        // epilogue: C/D layout col=lane&15, row=(lane>>4)*4+j  [m89-verified]
#pragma unroll
        for (int mi = 0; mi < 4; ++mi) {
#pragma unroll
            for (int ni = 0; ni < 2; ++ni) {
                int col = ni * 16 + fr;
                int adr = mgq + col * 64 + (((mi * 4 + fq) ^ (col & 15)) << 2);
                f32x4 p = *(const f32x4*)(Mg + adr);
                int gcol = n0 + wc * 32 + col;
                int rowb = m0 + wr * 64 + mi * 16 + fq * 4;
#pragma unroll
                for (int j = 0; j < 4; ++j) {
                    float v = acc[mi][ni][j] + p[j];
                    if (OUT_MODE == 0) {
                        Cb[(size_t)(rowb + j) * N + gcol] = f2b(v);
                    } else {
                        Cf[(size_t)(rowb + j) * N + gcol] = v + bias[gcol];
                    }
                }
            }
        }
    }
}

// ---------------------------------------------------------------------------
// conv: V[m][e] = T[m][e] for e<256 (v0 pass-through);
//       else causal FIR over l with combined taps + boundary corr.
// Thread handles 4 channels x 2 consecutive positions (m even): adjacent
// positions share 12/13 FIR rows -> 14 row-loads per 2 outputs.
// ---------------------------------------------------------------------------
__global__ __launch_bounds__(256) void conv_kernel(
    const unsigned short* __restrict__ T, unsigned short* __restrict__ V,
    const float* __restrict__ H, const float* __restrict__ Beff,
    const float* __restrict__ Corr)
{
    int w  = blockIdx.x * 256 + threadIdx.x;   // 2048*256 work items
    int m  = (w >> 8) * 2;                     // even position; pair never
    int e0 = (w & 255) * 4;                    // crosses batch boundary
    const unsigned short* tp = T + (size_t)m * EDIM + e0;
    unsigned short*       vp = V + (size_t)m * EDIM + e0;
    if (e0 < 256) {                       // v0 pass-through (both rows)
        *(u32x2*)vp = *(const u32x2*)tp;
        *(u32x2*)(vp + EDIM) = *(const u32x2*)(tp + EDIM);
        return;
    }
    int l  = m & (L_SEQ - 1);
    int ch = e0 - 256;
    float4v b4 = *(const float4v*)(Beff + ch);
    float4v acc0 = b4, acc1 = b4;

    // acc1 tap i=0: row m+1
    {
        float4v h = *(const float4v*)(H + ch);      // H[0]
        us4 t = *(const us4*)(tp + EDIM);
        acc1[0] += h[0] * b2f(t[0]); acc1[1] += h[1] * b2f(t[1]);
        acc1[2] += h[2] * b2f(t[2]); acc1[3] += h[3] * b2f(t[3]);
    }
    int ni = (l < 12) ? l : 12;
    for (int i = 0; i <= ni; ++i) {                 // row m-i, taps h[i]/h[i+1]
        us4 t = *(const us4*)(tp - (size_t)i * EDIM);
        float4v h0 = *(const float4v*)(H + i * 768 + ch);
        acc0[0] += h0[0] * b2f(t[0]); acc0[1] += h0[1] * b2f(t[1]);
        acc0[2] += h0[2] * b2f(t[2]); acc0[3] += h0[3] * b2f(t[3]);
        if (i < 12) {
            float4v h1 = *(const float4v*)(H + (i + 1) * 768 + ch);
            acc1[0] += h1[0] * b2f(t[0]); acc1[1] += h1[1] * b2f(t[1]);
            acc1[2] += h1[2] * b2f(t[2]); acc1[3] += h1[3] * b2f(t[3]);
        }
    }
    if (l < 6) {   // bias boundary correction (intermediate zero-padding)
        float4v c = *(const float4v*)(Corr + l * 768 + ch);
        acc0[0] -= c[0]; acc0[1] -= c[1]; acc0[2] -= c[2]; acc0[3] -= c[3];
    }
    if (l + 1 < 6) {
        float4v c = *(const float4v*)(Corr + (l + 1) * 768 + ch);
        acc1[0] -= c[0]; acc1[1] -= c[1]; acc1[2] -= c[2]; acc1[3] -= c[3];
    }
    us4 o0, o1;
    o0[0] = f2b(acc0[0]); o0[1] = f2b(acc0[1]); o0[2] = f2b(acc0[2]); o0[3] = f2b(acc0[3]);
    o1[0] = f2b(acc1[0]); o1[1] = f2b(acc1[1]); o1[2] = f2b(acc1[2]); o1[3] = f2b(acc1[3]);
    *(us4*)vp = o0;
    *(us4*)(vp + EDIM) = o1;
}

// ---------------------------------------------------------------------------
extern "C" void kernel_launch(void* const* d_in, const int* in_sizes, int n_in,
                              void* d_out, int out_size, void* d_ws, size_t ws_size,
                              hipStream_t stream)
{
    const float* x  = (const float*)d_in[0];
    const float* Wq = (const float*)d_in[1];
    // d_in[2] = Wk (dead: attention output is multiplied by 0.0)
    const float* Wv = (const float*)d_in[3];
    const float* Wo = (const float*)d_in[4];
    const float* bo = (const float*)d_in[5];

    uint8_t* ws = (uint8_t*)d_ws;
    unsigned short* W1b = (unsigned short*)(ws);                    //  2 MB
    unsigned short* Wob = (unsigned short*)(ws + (2u  << 20));      //  2 MB
    unsigned short* T   = (unsigned short*)(ws + (4u  << 20));      //  8 MB
    unsigned short* V   = (unsigned short*)(ws + (12u << 20));      //  8 MB
    float* H    = (float*)(ws + (20u << 20));                        // 40 KB
    float* Beff = (float*)(ws + (20u << 20) + (64u << 10));          //  3 KB
    float* Corr = (float*)(ws + (20u << 20) + (96u << 10));          // 18 KB

    wprep_kernel<<<2051, 256, 0, stream>>>(
        Wq, Wv, Wo, W1b, Wob,
        (const float*)d_in[6],  (const float*)d_in[7],
        (const float*)d_in[10], (const float*)d_in[11],
        (const float*)d_in[12], (const float*)d_in[13],
        (const float*)d_in[16], (const float*)d_in[17],
        (const float*)d_in[18], (const float*)d_in[19],
        (const float*)d_in[22], (const float*)d_in[23],
        H, Beff, Corr);

    dim3 gg(EDIM / 64, MTOT / 128);   // (16, 32) = 512 blocks, 2 per CU
    gemm_rs<1, 0><<<gg, 512, 0, stream>>>(x, nullptr, W1b, T, nullptr, nullptr,
                                          MTOT, EDIM, EDIM);

    conv_kernel<<<2048, 256, 0, stream>>>(T, V, H, Beff, Corr);

    gemm_rs<0, 1><<<gg, 512, 0, stream>>>(nullptr, V, Wob, nullptr, (float*)d_out, bo,
                                          MTOT, EDIM, EDIM);
}

// Round 7
// 53.419 us; speedup vs baseline: 1.1130x; 1.1130x over previous
//
#include <hip/hip_runtime.h>
#include <hip/hip_bf16.h>
#include <stdint.h>

// Problem constants: B=2, L=2048, E=1024, H=16, HD=64, G=4.
#define L_SEQ 2048
#define MTOT  4096   // B*L
#define EDIM  1024

typedef __attribute__((ext_vector_type(8))) short bf16x8;   // 8 bf16 (4 VGPRs)
typedef __attribute__((ext_vector_type(4))) float f32x4;
typedef __attribute__((ext_vector_type(4))) float float4v;
typedef __attribute__((ext_vector_type(4))) unsigned short us4;

__device__ __forceinline__ unsigned short f2b(float f) {
    union { float f; unsigned u; } v; v.f = f;
    return (unsigned short)((v.u + 0x7FFFu + ((v.u >> 16) & 1u)) >> 16);  // RNE
}
__device__ __forceinline__ float b2f(unsigned short h) {
    union { unsigned u; float f; } v; v.u = ((unsigned)h) << 16;
    return v.f;
}
__device__ __forceinline__ unsigned cvtpk(float lo, float hi) {   // RNE pack
    unsigned r;
    asm("v_cvt_pk_bf16_f32 %0, %1, %2" : "=v"(r) : "v"(lo), "v"(hi));
    return r;
}

__device__ __forceinline__ void lds16(const void* g, void* l) {
    __builtin_amdgcn_global_load_lds((const __attribute__((address_space(1))) void*)g,
                                     (__attribute__((address_space(3))) void*)l, 16, 0, 0);
}

// ---------------------------------------------------------------------------
// wprep: convert W1 (stitched [Wv rows 0..255 ; Wq rows 256..1023]) and Wo
//        to bf16. Blocks >= 2048 compute the composed FIR taps.
// ---------------------------------------------------------------------------
__global__ __launch_bounds__(256) void wprep_kernel(
    const float* __restrict__ Wq, const float* __restrict__ Wv,
    const float* __restrict__ Wo,
    unsigned short* __restrict__ W1b, unsigned short* __restrict__ Wob,
    const float* __restrict__ q3w, const float* __restrict__ q3b,
    const float* __restrict__ v3w, const float* __restrict__ v3b,
    const float* __restrict__ q5w, const float* __restrict__ q5b,
    const float* __restrict__ v5w, const float* __restrict__ v5b,
    const float* __restrict__ q7w, const float* __restrict__ q7b,
    const float* __restrict__ v7w, const float* __restrict__ v7b,
    float* __restrict__ H, float* __restrict__ Beff, float* __restrict__ Corr)
{
    if (blockIdx.x >= 2048) {
        // taps: compose the two causal depthwise convs per channel.
        //   dwconv taps h[i] = w[k-1-i]; chain h = hq (*) hv (len 2k-1<=13),
        //   beff = vb + qb*sum(vw); boundary (l<k-1): intermediate zero-pad
        //   drops qb for taps i>l -> Corr[l][ch] = qb*sum_{i=l+1..} hv[i].
        int ch = (blockIdx.x - 2048) * 256 + threadIdx.x;   // [0,768)
        int g = ch >> 8;          // 0,1,2 -> ksz 3,5,7
        int d = ch & 63;
        int k = 3 + 2 * g;
        const float* qw = (g == 0) ? q3w : (g == 1) ? q5w : q7w;
        const float* qb = (g == 0) ? q3b : (g == 1) ? q5b : q7b;
        const float* vw = (g == 0) ? v3w : (g == 1) ? v5w : v7w;
        const float* vb = (g == 0) ? v3b : (g == 1) ? v5b : v7b;

        float hq[7], hv[7];
        for (int i = 0; i < 7; ++i) { hq[i] = 0.f; hv[i] = 0.f; }
        for (int i = 0; i < k; ++i) {
            hq[i] = qw[d * k + (k - 1 - i)];
            hv[i] = vw[d * k + (k - 1 - i)];
        }
        float h[13];
        for (int i = 0; i < 13; ++i) h[i] = 0.f;
        for (int a = 0; a < 7; ++a)
            for (int b = 0; b < 7; ++b)
                h[a + b] += hq[a] * hv[b];
        for (int i = 0; i < 13; ++i) H[i * 768 + ch] = h[i];

        float sv = 0.f;
        for (int j = 0; j < k; ++j) sv += vw[d * k + j];
        Beff[ch] = qb[d] * sv + vb[d];

        for (int l = 0; l < 6; ++l) {
            float s2 = 0.f;
            for (int i = l + 1; i < 7; ++i) s2 += hv[i];
            Corr[l * 768 + ch] = qb[d] * s2;
        }
        return;
    }
    const int WQ = (EDIM * EDIM) / 4;   // 262,144 quads per matrix
    int i = blockIdx.x * 256 + threadIdx.x;
    const float* src;
    unsigned short* dst;
    int j;
    if (i < WQ) {
        j = i * 4;
        int row = j >> 10;                 // /1024
        src = (row < 256) ? Wv : Wq;       // stitched W1
        dst = W1b;
    } else {
        j = (i - WQ) * 4; src = Wo; dst = Wob;
    }
    float4v v = *(const float4v*)(src + j);
    us4 o;
    o[0] = f2b(v[0]); o[1] = f2b(v[1]); o[2] = f2b(v[2]); o[3] = f2b(v[3]);
    *(us4*)(dst + j) = o;
}

// ---------------------------------------------------------------------------
// GEMM (R5 mechanism: 8-wave K-split, 64x64 wave tiles, gload_lds staging,
// counted-vmcnt 3-buffer pipeline, XOR bank swizzle, XCD remap).
//   C[M=4096, N=1024] = A[.,K=1024] * BT[N,K]^T.  BM=BN=128, BK=64.
//   512 thr = 8 waves: 2x2 spatial (wr,wc) x 2 K-halves (kh); acc 4x4.
//   TA=1: A staged as RAW FP32 (x), fragments packed to bf16 in-register via
//         v_cvt_pk_bf16_f32 (fuses the old prep pass). A-buf 32KB, LDS 144KB.
//   TA=0: A bf16, per-tile source switch (t<tsplit ? Ab0 : Ab1) -- lets gemm2
//         read the v0 pass-through columns straight from T. LDS 96KB.
//   Pipeline: depth 2 (tiles t+1,t+2 in flight), steady wait vmcnt(LPT)
//   (LPT = loads/thread/tile: 6 fp32-A, 4 bf16-A). Never vmcnt(0) mid-loop.
//   Swizzles (both-sides XOR involutions, pre-swizzled global source +
//   swizzled ds_read): bf16 tiles colgrp^=(row&7) @16B-grp; fp32 A tile
//   chunk^=(row&15) @16B-chunk. K-split merge via LDS at the end.
// OUT_MODE 0: bf16 store. OUT_MODE 1: f32 store + bias[col].
// ---------------------------------------------------------------------------
template <int TA, int OUT_MODE>
__global__ __launch_bounds__(512, 2) void gemm_f(
    const float* __restrict__ Af,
    const unsigned short* __restrict__ Ab0, const unsigned short* __restrict__ Ab1,
    int tsplit,
    const unsigned short* __restrict__ BT,
    unsigned short* __restrict__ Cb, float* __restrict__ Cf,
    const float* __restrict__ bias)
{
    constexpr int ABUF = TA ? 49152 : 32768;   // bytes per buffer (A+B)
    constexpr int ABYT = TA ? 32768 : 16384;   // A bytes within buffer
    __shared__ uint8_t sh[3 * ABUF];

    // XCD-aware remap (256 blocks, %8==0 -> bijective chunked).
    int orig = blockIdx.y * 8 + blockIdx.x;
    int wg   = (orig & 7) * 32 + (orig >> 3);
    const int m0 = (wg >> 3) * 128, n0 = (wg & 7) * 128;

    const int tid  = threadIdx.x;
    const int wid  = tid >> 6;                    // 0..7
    const int lane = tid & 63;
    const int wr   = wid >> 2;                    // 2x2 spatial
    const int wc   = (wid >> 1) & 1;
    const int kh   = wid & 1;                     // K-half
    const int fr   = lane & 15, fq = lane >> 4;

    f32x4 acc[4][4] = {};

    auto stage = [&](int buf, int t) {
        uint8_t* Abase = sh + buf * ABUF;
        uint8_t* Bbase = Abase + ABYT;
        if (TA) {
            const float* Asrc = Af + (size_t)m0 * EDIM + t * 64;
#pragma unroll
            for (int j = 0; j < 4; ++j) {         // 2048 fp32 16B-chunks
                int slot = j * 512 + tid;
                int row = slot >> 4, c = (slot & 15) ^ (row & 15);
                lds16(Asrc + (size_t)row * EDIM + c * 4,
                      Abase + j * 8192 + wid * 1024);
            }
        } else {
            const unsigned short* Asrc =
                (t < tsplit ? Ab0 : Ab1) + (size_t)m0 * EDIM + t * 64;
#pragma unroll
            for (int j = 0; j < 2; ++j) {         // 1024 bf16 16B-chunks
                int slot = j * 512 + tid;
                int row = slot >> 3, c = (slot & 7) ^ (row & 7);
                lds16(Asrc + (size_t)row * EDIM + c * 8,
                      Abase + j * 8192 + wid * 1024);
            }
        }
        const unsigned short* Bsrc = BT + (size_t)n0 * EDIM + t * 64;
#pragma unroll
        for (int j = 0; j < 2; ++j) {
            int slot = j * 512 + tid;
            int row = slot >> 3, c = (slot & 7) ^ (row & 7);
            lds16(Bsrc + (size_t)row * EDIM + c * 8,
                  Bbase + j * 8192 + wid * 1024);
        }
    };

    auto compute = [&](int buf) {
        const uint8_t* Abase = sh + buf * ABUF;
        const unsigned short* bs = (const unsigned short*)(Abase + ABYT);
        bf16x8 a[4], b[4];
#pragma unroll
        for (int mi = 0; mi < 4; ++mi) {
            int row = wr * 64 + mi * 16 + fr;
            if (TA) {
                const float* as = (const float*)Abase;
                int c0 = kh * 8 + fq * 2;
                f32x4 lo = *(const f32x4*)(as + row * 64 + ((c0 ^ (row & 15)) * 4));
                f32x4 hi = *(const f32x4*)(as + row * 64 + (((c0 + 1) ^ (row & 15)) * 4));
                union { unsigned u[4]; bf16x8 v; } fu;
                fu.u[0] = cvtpk(lo[0], lo[1]); fu.u[1] = cvtpk(lo[2], lo[3]);
                fu.u[2] = cvtpk(hi[0], hi[1]); fu.u[3] = cvtpk(hi[2], hi[3]);
                a[mi] = fu.v;
            } else {
                const unsigned short* as = (const unsigned short*)Abase;
                a[mi] = *(const bf16x8*)(as + row * 64 + (((kh * 4 + fq) ^ (row & 7)) * 8));
            }
        }
#pragma unroll
        for (int ni = 0; ni < 4; ++ni) {
            int row = wc * 64 + ni * 16 + fr;
            b[ni] = *(const bf16x8*)(bs + row * 64 + (((kh * 4 + fq) ^ (row & 7)) * 8));
        }
#pragma unroll
        for (int mi = 0; mi < 4; ++mi)
#pragma unroll
            for (int ni = 0; ni < 4; ++ni)
                acc[mi][ni] = __builtin_amdgcn_mfma_f32_16x16x32_bf16(a[mi], b[ni], acc[mi][ni], 0, 0, 0);
    };

    const int NT = EDIM >> 6;   // 16 K-tiles
    stage(0, 0);
    stage(1, 1);
    if (TA) asm volatile("s_waitcnt vmcnt(6)" ::: "memory");   // tile 0 landed
    else    asm volatile("s_waitcnt vmcnt(4)" ::: "memory");
    __builtin_amdgcn_s_barrier();
    asm volatile("" ::: "memory");

    for (int t = 0; t < NT; ++t) {
        if (t + 2 < NT) stage((t + 2) % 3, t + 2);
        compute(t % 3);
        if (t + 1 < NT) {
            if (t + 2 < NT) {
                if (TA) asm volatile("s_waitcnt vmcnt(6)" ::: "memory");
                else    asm volatile("s_waitcnt vmcnt(4)" ::: "memory");
            } else {
                asm volatile("s_waitcnt vmcnt(0)" ::: "memory");  // drain tail
            }
            __builtin_amdgcn_s_barrier();
            asm volatile("" ::: "memory");
        }
    }

    // ---- K-split merge: kh=1 dumps partials to LDS, kh=0 adds & stores. ----
    __syncthreads();   // all MFMA reads of sh complete before overwrite
    float* Mg = (float*)sh;            // 64KB needed, fits both variants
    const int mgbase = (wr * 2 + wc) * 4096;
    if (kh) {
#pragma unroll
        for (int mi = 0; mi < 4; ++mi)
#pragma unroll
            for (int ni = 0; ni < 4; ++ni) {
                int col = ni * 16 + fr;
                int adr = mgbase + col * 64 + (((mi * 4 + fq) ^ (col & 15)) << 2);
                *(f32x4*)(Mg + adr) = acc[mi][ni];
            }
    }
    __syncthreads();
    if (!kh) {
        // epilogue: C/D layout col=lane&15, row=(lane>>4)*4+j  [m89-verified]
#pragma unroll
        for (int mi = 0; mi < 4; ++mi) {
#pragma unroll
            for (int ni = 0; ni < 4; ++ni) {
                int col = ni * 16 + fr;
                int adr = mgbase + col * 64 + (((mi * 4 + fq) ^ (col & 15)) << 2);
                f32x4 p = *(const f32x4*)(Mg + adr);
                int gcol = n0 + wc * 64 + col;
                int rowb = m0 + wr * 64 + mi * 16 + fq * 4;
#pragma unroll
                for (int j = 0; j < 4; ++j) {
                    float v = acc[mi][ni][j] + p[j];
                    if (OUT_MODE == 0) {
                        Cb[(size_t)(rowb + j) * EDIM + gcol] = f2b(v);
                    } else {
                        Cf[(size_t)(rowb + j) * EDIM + gcol] = v + bias[gcol];
                    }
                }
            }
        }
    }
}

// ---------------------------------------------------------------------------
// conv: causal FIR on cols 256..1023 only (v0 cols are read from T directly
// by gemm2's t<4 tiles). Thread: 4 channels x 2 consecutive positions.
// ---------------------------------------------------------------------------
__global__ __launch_bounds__(256) void conv_kernel(
    const unsigned short* __restrict__ T, unsigned short* __restrict__ V,
    const float* __restrict__ H, const float* __restrict__ Beff,
    const float* __restrict__ Corr)
{
    unsigned w  = blockIdx.x * 256 + threadIdx.x;   // 2048 rowpairs x 192 quads
    unsigned rp = w / 192u;
    int c4 = (int)(w - rp * 192u);
    int m  = (int)rp * 2;                           // pair never crosses batch
    int ch = c4 * 4;                                // [0,768)
    int e0 = 256 + ch;
    const unsigned short* tp = T + (size_t)m * EDIM + e0;
    unsigned short*       vp = V + (size_t)m * EDIM + e0;
    int l  = m & (L_SEQ - 1);
    float4v b4 = *(const float4v*)(Beff + ch);
    float4v acc0 = b4, acc1 = b4;

    // acc1 tap i=0: row m+1
    {
        float4v h = *(const float4v*)(H + ch);      // H[0]
        us4 t = *(const us4*)(tp + EDIM);
        acc1[0] += h[0] * b2f(t[0]); acc1[1] += h[1] * b2f(t[1]);
        acc1[2] += h[2] * b2f(t[2]); acc1[3] += h[3] * b2f(t[3]);
    }
    int ni = (l < 12) ? l : 12;
    for (int i = 0; i <= ni; ++i) {                 // row m-i, taps h[i]/h[i+1]
        us4 t = *(const us4*)(tp - (size_t)i * EDIM);
        float4v h0 = *(const float4v*)(H + i * 768 + ch);
        acc0[0] += h0[0] * b2f(t[0]); acc0[1] += h0[1] * b2f(t[1]);
        acc0[2] += h0[2] * b2f(t[2]); acc0[3] += h0[3] * b2f(t[3]);
        if (i < 12) {
            float4v h1 = *(const float4v*)(H + (i + 1) * 768 + ch);
            acc1[0] += h1[0] * b2f(t[0]); acc1[1] += h1[1] * b2f(t[1]);
            acc1[2] += h1[2] * b2f(t[2]); acc1[3] += h1[3] * b2f(t[3]);
        }
    }
    if (l < 6) {   // bias boundary correction (intermediate zero-padding)
        float4v c = *(const float4v*)(Corr + l * 768 + ch);
        acc0[0] -= c[0]; acc0[1] -= c[1]; acc0[2] -= c[2]; acc0[3] -= c[3];
    }
    if (l + 1 < 6) {
        float4v c = *(const float4v*)(Corr + (l + 1) * 768 + ch);
        acc1[0] -= c[0]; acc1[1] -= c[1]; acc1[2] -= c[2]; acc1[3] -= c[3];
    }
    us4 o0, o1;
    o0[0] = f2b(acc0[0]); o0[1] = f2b(acc0[1]); o0[2] = f2b(acc0[2]); o0[3] = f2b(acc0[3]);
    o1[0] = f2b(acc1[0]); o1[1] = f2b(acc1[1]); o1[2] = f2b(acc1[2]); o1[3] = f2b(acc1[3]);
    *(us4*)vp = o0;
    *(us4*)(vp + EDIM) = o1;
}

// ---------------------------------------------------------------------------
extern "C" void kernel_launch(void* const* d_in, const int* in_sizes, int n_in,
                              void* d_out, int out_size, void* d_ws, size_t ws_size,
                              hipStream_t stream)
{
    const float* x  = (const float*)d_in[0];
    const float* Wq = (const float*)d_in[1];
    // d_in[2] = Wk (dead: attention output is multiplied by 0.0)
    const float* Wv = (const float*)d_in[3];
    const float* Wo = (const float*)d_in[4];
    const float* bo = (const float*)d_in[5];

    uint8_t* ws = (uint8_t*)d_ws;
    unsigned short* W1b = (unsigned short*)(ws);                    //  2 MB
    unsigned short* Wob = (unsigned short*)(ws + (2u  << 20));      //  2 MB
    unsigned short* T   = (unsigned short*)(ws + (4u  << 20));      //  8 MB
    unsigned short* V   = (unsigned short*)(ws + (12u << 20));      //  8 MB
    float* H    = (float*)(ws + (20u << 20));                        // 40 KB
    float* Beff = (float*)(ws + (20u << 20) + (64u << 10));          //  3 KB
    float* Corr = (float*)(ws + (20u << 20) + (96u << 10));          // 18 KB

    wprep_kernel<<<2051, 256, 0, stream>>>(
        Wq, Wv, Wo, W1b, Wob,
        (const float*)d_in[6],  (const float*)d_in[7],
        (const float*)d_in[10], (const float*)d_in[11],
        (const float*)d_in[12], (const float*)d_in[13],
        (const float*)d_in[16], (const float*)d_in[17],
        (const float*)d_in[18], (const float*)d_in[19],
        (const float*)d_in[22], (const float*)d_in[23],
        H, Beff, Corr);

    dim3 gg(EDIM / 128, MTOT / 128);   // (8, 32) = 256 blocks
    // gemm1: T = x @ W1^T, A read as raw fp32 (prep fused away)
    gemm_f<1, 0><<<gg, 512, 0, stream>>>(x, nullptr, nullptr, 0,
                                         W1b, T, nullptr, nullptr);

    conv_kernel<<<1536, 256, 0, stream>>>(T, V, H, Beff, Corr);

    // gemm2: out = [T[:, :256] | V[:, 256:]] @ Wo^T + bo  (tsplit=4 tiles)
    gemm_f<0, 1><<<gg, 512, 0, stream>>>(nullptr, T, V, 4,
                                         Wob, nullptr, (float*)d_out, bo);
}